// Round 1
// baseline (1327.299 us; speedup 1.0000x reference)
//
#include <hip/hip_runtime.h>

#define BN_EPS 1e-5f

// ---------------- embedding: h = x @ W_emb + b_emb  (x is [N,4]) ----------------
__global__ void k_embed(const float* __restrict__ x, const float* __restrict__ Wemb,
                        const float* __restrict__ bemb, float* __restrict__ h, int N) {
    int t = blockIdx.x * blockDim.x + threadIdx.x;
    int n = t >> 6, c = t & 63;
    if (n >= N) return;
    const float* xr = x + (size_t)n * 4;
    float acc = bemb[c];
    acc += xr[0] * Wemb[0 * 64 + c];
    acc += xr[1] * Wemb[1 * 64 + c];
    acc += xr[2] * Wemb[2 * 64 + c];
    acc += xr[3] * Wemb[3 * 64 + c];
    h[t] = acc;  // t == n*64+c
}

// ---------------- deg_w[i] = sum of EdgeAttr over incoming edges ----------------
__global__ void k_degw(const int* __restrict__ dst, const float* __restrict__ attr,
                       float* __restrict__ degw, int E) {
    int e = blockIdx.x * blockDim.x + threadIdx.x;
    if (e < E) atomicAdd(&degw[dst[e]], attr[e]);
}

// ---------------- S[dst] += w * h[src]  (one wave per edge, lane = channel) -----
__global__ void k_scatter(const int* __restrict__ src, const int* __restrict__ dst,
                          const float* __restrict__ attr, const float* __restrict__ h,
                          float* __restrict__ S, int E) {
    int t = blockIdx.x * blockDim.x + threadIdx.x;
    int e = t >> 6, c = t & 63;
    if (e >= E) return;
    int s = src[e], d = dst[e];
    float w = attr[e];
    atomicAdd(&S[d * 64 + c], w * h[s * 64 + c]);
}

// ---------------- hn = S@W1 + h@W3 - degw*(h@W2) + degw*b1 + b3 ; BN partials ---
__global__ __launch_bounds__(256) void k_update(
    const float* __restrict__ S, const float* __restrict__ h,
    const float* __restrict__ degw,
    const float* __restrict__ W1, const float* __restrict__ b1,
    const float* __restrict__ W2, const float* __restrict__ W3,
    const float* __restrict__ b3,
    float* __restrict__ hn, float* __restrict__ bnstats, int N) {
    __shared__ float W1s[64 * 64], W2s[64 * 64], W3s[64 * 64];
    __shared__ float sS[16 * 64], sh[16 * 64];
    __shared__ float dwS[16];
    int tid = threadIdx.x;
    // stage weights once per block (reused across grid-stride tile loop)
    for (int i = tid * 4; i < 4096; i += 1024) {
        *(float4*)&W1s[i] = *(const float4*)&W1[i];
        *(float4*)&W2s[i] = *(const float4*)&W2[i];
        *(float4*)&W3s[i] = *(const float4*)&W3[i];
    }
    int c = tid & 63, w = tid >> 6;
    float b1c = b1[c], b3c = b3[c];
    float bsum = 0.f, bsq = 0.f;
    int numTiles = (N + 15) / 16;
    for (int tile = blockIdx.x; tile < numTiles; tile += gridDim.x) {
        int n0 = tile * 16;
        __syncthreads();  // protect LDS tile from previous iteration's readers
        {
            int idx = tid * 4;           // 1024 floats per array, 4 per thread
            int nrow = idx >> 6;
            if (n0 + nrow < N) {
                int base = n0 * 64;
                *(float4*)&sS[idx] = *(const float4*)&S[base + idx];
                *(float4*)&sh[idx] = *(const float4*)&h[base + idx];
            } else {
                sS[idx] = sS[idx + 1] = sS[idx + 2] = sS[idx + 3] = 0.f;
                sh[idx] = sh[idx + 1] = sh[idx + 2] = sh[idx + 3] = 0.f;
            }
            if (tid < 16) dwS[tid] = (n0 + tid < N) ? degw[n0 + tid] : 0.f;
        }
        __syncthreads();
        float aA[4] = {0, 0, 0, 0}, aB[4] = {0, 0, 0, 0}, aC[4] = {0, 0, 0, 0};
        for (int k = 0; k < 64; ++k) {
            float w1 = W1s[k * 64 + c], w2 = W2s[k * 64 + c], w3 = W3s[k * 64 + c];
#pragma unroll
            for (int m = 0; m < 4; ++m) {
                int nl = w + 4 * m;
                float sv = sS[nl * 64 + k], hv = sh[nl * 64 + k];
                aA[m] += sv * w1;
                aB[m] += hv * w2;
                aC[m] += hv * w3;
            }
        }
#pragma unroll
        for (int m = 0; m < 4; ++m) {
            int nl = w + 4 * m;
            int n = n0 + nl;
            if (n < N) {
                float dw = dwS[nl];
                float val = aA[m] + aC[m] - dw * aB[m] + dw * b1c + b3c;
                hn[n * 64 + c] = val;
                bsum += val;
                bsq += val * val;
            }
        }
    }
    // BN partial reduction: reuse sS
    __syncthreads();
    sS[tid] = bsum;
    sS[256 + tid] = bsq;
    __syncthreads();
    if (tid < 64) {
        float s = sS[tid] + sS[tid + 64] + sS[tid + 128] + sS[tid + 192];
        float q = sS[256 + tid] + sS[256 + tid + 64] + sS[256 + tid + 128] + sS[256 + tid + 192];
        atomicAdd(&bnstats[tid], s);
        atomicAdd(&bnstats[64 + tid], q);
    }
}

// ---------------- finalize BN: scale/shift per channel ----------------
__global__ void k_bnfinish(const float* __restrict__ bnstats,
                           const float* __restrict__ gamma, const float* __restrict__ beta,
                           float* __restrict__ scale, float* __restrict__ shift, int N) {
    int c = threadIdx.x;
    float inv_n = 1.0f / (float)N;
    float mean = bnstats[c] * inv_n;
    float var = bnstats[64 + c] * inv_n - mean * mean;
    float sc = gamma[c] * rsqrtf(fmaxf(var, 0.f) + BN_EPS);
    scale[c] = sc;
    shift[c] = beta[c] - mean * sc;
}

// ---------------- apply BN + ReLU (float4) ----------------
__global__ void k_bnapply(const float* __restrict__ hn, const float* __restrict__ scale,
                          const float* __restrict__ shift, float* __restrict__ h, int N) {
    int t = blockIdx.x * blockDim.x + threadIdx.x;
    if (t >= N * 16) return;
    int idx = t * 4;
    int c = idx & 63;
    float4 v = *(const float4*)&hn[idx];
    float4 sc = *(const float4*)&scale[c];
    float4 sf = *(const float4*)&shift[c];
    float4 r;
    r.x = fmaxf(v.x * sc.x + sf.x, 0.f);
    r.y = fmaxf(v.y * sc.y + sf.y, 0.f);
    r.z = fmaxf(v.z * sc.z + sf.z, 0.f);
    r.w = fmaxf(v.w * sc.w + sf.w, 0.f);
    *(float4*)&h[idx] = r;
}

// ---------------- pool per graph (sorted batch, binary search) + MLP head -------
__global__ void k_pool(const float* __restrict__ h, const int* __restrict__ batch,
                       const float* __restrict__ Wl1, const float* __restrict__ bl1,
                       const float* __restrict__ Wl2, const float* __restrict__ bl2,
                       float* __restrict__ out, int N) {
    int g = blockIdx.x;
    int c = threadIdx.x;  // 64 threads
    // first index with batch >= g, first with batch >= g+1 (uniform per block)
    int lo = 0, hi = N;
    while (lo < hi) { int mid = (lo + hi) >> 1; if (batch[mid] < g) lo = mid + 1; else hi = mid; }
    int start = lo;
    hi = N;
    while (lo < hi) { int mid = (lo + hi) >> 1; if (batch[mid] < g + 1) lo = mid + 1; else hi = mid; }
    int end = lo;
    float acc = 0.f;
    for (int n = start; n < end; ++n) acc += h[n * 64 + c];
    int cnt = end - start;
    float denom = (float)(cnt > 0 ? cnt : 1);
    __shared__ float gS[64], yS[64];
    gS[c] = acc / denom;
    __syncthreads();
    float y = bl1[c];
    for (int k = 0; k < 64; ++k) y += gS[k] * Wl1[k * 64 + c];
    yS[c] = fmaxf(y, 0.f);
    __syncthreads();
    if (c < 3) {
        float o = bl2[c];
        for (int k = 0; k < 64; ++k) o += yS[k] * Wl2[k * 3 + c];
        out[g * 3 + c] = o;
    }
}

extern "C" void kernel_launch(void* const* d_in, const int* in_sizes, int n_in,
                              void* d_out, int out_size, void* d_ws, size_t ws_size,
                              hipStream_t stream) {
    const float* x     = (const float*)d_in[0];
    const int*   eid   = (const int*)d_in[1];
    const float* attr  = (const float*)d_in[2];
    const int*   batch = (const int*)d_in[3];
    const float* Wemb  = (const float*)d_in[4];
    const float* bemb  = (const float*)d_in[5];
    const float* W1    = (const float*)d_in[6];
    const float* b1    = (const float*)d_in[7];
    const float* W2    = (const float*)d_in[8];
    const float* W3    = (const float*)d_in[9];
    const float* b3    = (const float*)d_in[10];
    const float* gamma = (const float*)d_in[11];
    const float* beta  = (const float*)d_in[12];
    const float* Wl1   = (const float*)d_in[13];
    const float* bl1   = (const float*)d_in[14];
    const float* Wl2   = (const float*)d_in[15];
    const float* bl2   = (const float*)d_in[16];

    int N = in_sizes[3];         // batch has N entries
    int E = in_sizes[2];         // EdgeAttr has E entries
    int L = in_sizes[7] / 64;    // b1 is [L,64]
    int G = out_size / 3;        // NUM_GRAPHS

    const int* src = eid;
    const int* dst = eid + E;

    float* ws      = (float*)d_ws;
    float* h       = ws;
    float* hn      = h + (size_t)N * 64;
    float* S       = hn + (size_t)N * 64;
    float* degw    = S + (size_t)N * 64;
    float* bnstats = degw + N;       // 128 floats
    float* bnscale = bnstats + 128;  // 64
    float* bnshift = bnscale + 64;   // 64

    hipMemsetAsync(degw, 0, (size_t)N * sizeof(float), stream);
    k_embed<<<(N * 64 + 255) / 256, 256, 0, stream>>>(x, Wemb, bemb, h, N);
    k_degw<<<(E + 255) / 256, 256, 0, stream>>>(dst, attr, degw, E);

    for (int l = 0; l < L; ++l) {
        hipMemsetAsync(S, 0, (size_t)N * 64 * sizeof(float), stream);
        hipMemsetAsync(bnstats, 0, 128 * sizeof(float), stream);
        k_scatter<<<(int)(((long long)E * 64 + 255) / 256), 256, 0, stream>>>(src, dst, attr, h, S, E);
        k_update<<<512, 256, 0, stream>>>(S, h, degw,
                                          W1 + (size_t)l * 4096, b1 + (size_t)l * 64,
                                          W2 + (size_t)l * 4096, W3 + (size_t)l * 4096,
                                          b3 + (size_t)l * 64, hn, bnstats, N);
        k_bnfinish<<<1, 64, 0, stream>>>(bnstats, gamma + (size_t)l * 64, beta + (size_t)l * 64,
                                         bnscale, bnshift, N);
        k_bnapply<<<(N * 16 + 255) / 256, 256, 0, stream>>>(hn, bnscale, bnshift, h, N);
    }

    k_pool<<<G, 64, 0, stream>>>(h, batch, Wl1, bl1, Wl2, bl2, (float*)d_out, N);
}

// Round 2
// 1033.253 us; speedup vs baseline: 1.2846x; 1.2846x over previous
//
#include <hip/hip_runtime.h>

#define BN_EPS 1e-5f

// ---------------- embedding: h = x @ W_emb + b_emb  (x is [N,4]) ----------------
__global__ void k_embed(const float* __restrict__ x, const float* __restrict__ Wemb,
                        const float* __restrict__ bemb, float* __restrict__ h, int N) {
    int t = blockIdx.x * blockDim.x + threadIdx.x;
    int n = t >> 6, c = t & 63;
    if (n >= N) return;
    const float* xr = x + (size_t)n * 4;
    float acc = bemb[c];
    acc += xr[0] * Wemb[0 * 64 + c];
    acc += xr[1] * Wemb[1 * 64 + c];
    acc += xr[2] * Wemb[2 * 64 + c];
    acc += xr[3] * Wemb[3 * 64 + c];
    h[t] = acc;  // t == n*64+c
}

// ---------------- CSR build: histogram of dst ----------------
__global__ void k_hist(const int* __restrict__ dst, int* __restrict__ deg, int E) {
    int e = blockIdx.x * blockDim.x + threadIdx.x;
    if (e < E) atomicAdd(&deg[dst[e]], 1);
}

// ---------------- CSR build: exclusive scan (single block, 1024 threads) --------
__global__ __launch_bounds__(1024) void k_scan(const int* __restrict__ deg,
                                               int* __restrict__ rowptr,
                                               int* __restrict__ cursor, int N) {
    __shared__ int tsum[1024];
    int tid = threadIdx.x;
    int chunk = (N + 1023) / 1024;
    int lo = tid * chunk;
    int hi = lo + chunk; if (hi > N) hi = N;
    int s = 0;
    for (int i = lo; i < hi; ++i) s += deg[i];
    tsum[tid] = s;
    __syncthreads();
    // Hillis-Steele inclusive scan over thread sums
    for (int d = 1; d < 1024; d <<= 1) {
        int v = (tid >= d) ? tsum[tid - d] : 0;
        __syncthreads();
        tsum[tid] += v;
        __syncthreads();
    }
    int run = (tid == 0) ? 0 : tsum[tid - 1];
    for (int i = lo; i < hi; ++i) {
        rowptr[i] = run;
        cursor[i] = run;
        run += deg[i];
    }
    if (hi == N && lo <= N) rowptr[N] = tsum[1023];
}

// ---------------- CSR build: fill sorted-by-dst edge arrays ----------------
__global__ void k_fill(const int* __restrict__ src, const int* __restrict__ dst,
                       const float* __restrict__ attr, int* __restrict__ cursor,
                       int* __restrict__ csrc, float* __restrict__ cattr, int E) {
    int e = blockIdx.x * blockDim.x + threadIdx.x;
    if (e >= E) return;
    int d = dst[e];
    int pos = atomicAdd(&cursor[d], 1);
    csrc[pos] = src[e];
    cattr[pos] = attr[e];
}

// ---------------- pull gather: S[n] = sum_e w_e * h[src_e]; degw[n] = sum w_e ---
__global__ void k_gather(const int* __restrict__ rowptr, const int* __restrict__ csrc,
                         const float* __restrict__ cattr, const float* __restrict__ h,
                         float* __restrict__ S, float* __restrict__ degw, int N) {
    int t = blockIdx.x * blockDim.x + threadIdx.x;
    int n = t >> 6, c = t & 63;
    if (n >= N) return;
    int beg = rowptr[n], end = rowptr[n + 1];
    float acc = 0.f, wsum = 0.f;
    int e = beg;
    for (; e + 1 < end; e += 2) {
        int s0 = csrc[e], s1 = csrc[e + 1];
        float w0 = cattr[e], w1 = cattr[e + 1];
        acc += w0 * h[(size_t)s0 * 64 + c];
        acc += w1 * h[(size_t)s1 * 64 + c];
        wsum += w0 + w1;
    }
    if (e < end) {
        int s0 = csrc[e];
        float w0 = cattr[e];
        acc += w0 * h[(size_t)s0 * 64 + c];
        wsum += w0;
    }
    S[(size_t)n * 64 + c] = acc;
    if (c == 0) degw[n] = wsum;
}

// ------- h = S@W1 + h@W3 - degw*(h@W2) + degw*b1 + b3 (in place); BN partials ---
__global__ __launch_bounds__(256) void k_update(
    const float* __restrict__ S, float* __restrict__ h,
    const float* __restrict__ degw,
    const float* __restrict__ W1, const float* __restrict__ b1,
    const float* __restrict__ W2, const float* __restrict__ W3,
    const float* __restrict__ b3,
    float* __restrict__ bnstats, int N) {
    __shared__ float W1s[64 * 64], W2s[64 * 64], W3s[64 * 64];
    __shared__ float sS[16 * 64], sh[16 * 64];
    __shared__ float dwS[16];
    int tid = threadIdx.x;
    // stage weights once per block (reused across grid-stride tile loop)
    for (int i = tid * 4; i < 4096; i += 1024) {
        *(float4*)&W1s[i] = *(const float4*)&W1[i];
        *(float4*)&W2s[i] = *(const float4*)&W2[i];
        *(float4*)&W3s[i] = *(const float4*)&W3[i];
    }
    int c = tid & 63, w = tid >> 6;
    float b1c = b1[c], b3c = b3[c];
    float bsum = 0.f, bsq = 0.f;
    int numTiles = (N + 15) / 16;
    for (int tile = blockIdx.x; tile < numTiles; tile += gridDim.x) {
        int n0 = tile * 16;
        __syncthreads();  // protect LDS tile from previous iteration's readers
        {
            int idx = tid * 4;           // 1024 floats per array, 4 per thread
            int nrow = idx >> 6;
            if (n0 + nrow < N) {
                int base = n0 * 64;
                *(float4*)&sS[idx] = *(const float4*)&S[base + idx];
                *(float4*)&sh[idx] = *(const float4*)&h[base + idx];
            } else {
                sS[idx] = sS[idx + 1] = sS[idx + 2] = sS[idx + 3] = 0.f;
                sh[idx] = sh[idx + 1] = sh[idx + 2] = sh[idx + 3] = 0.f;
            }
            if (tid < 16) dwS[tid] = (n0 + tid < N) ? degw[n0 + tid] : 0.f;
        }
        __syncthreads();
        float aA[4] = {0, 0, 0, 0}, aB[4] = {0, 0, 0, 0}, aC[4] = {0, 0, 0, 0};
        for (int k = 0; k < 64; ++k) {
            float w1 = W1s[k * 64 + c], w2 = W2s[k * 64 + c], w3 = W3s[k * 64 + c];
#pragma unroll
            for (int m = 0; m < 4; ++m) {
                int nl = w + 4 * m;
                float sv = sS[nl * 64 + k], hv = sh[nl * 64 + k];
                aA[m] += sv * w1;
                aB[m] += hv * w2;
                aC[m] += hv * w3;
            }
        }
#pragma unroll
        for (int m = 0; m < 4; ++m) {
            int nl = w + 4 * m;
            int n = n0 + nl;
            if (n < N) {
                float dw = dwS[nl];
                float val = aA[m] + aC[m] - dw * aB[m] + dw * b1c + b3c;
                h[(size_t)n * 64 + c] = val;  // in place: tile already staged in LDS
                bsum += val;
                bsq += val * val;
            }
        }
    }
    // BN partial reduction: reuse sS
    __syncthreads();
    sS[tid] = bsum;
    sS[256 + tid] = bsq;
    __syncthreads();
    if (tid < 64) {
        float s = sS[tid] + sS[tid + 64] + sS[tid + 128] + sS[tid + 192];
        float q = sS[256 + tid] + sS[256 + tid + 64] + sS[256 + tid + 128] + sS[256 + tid + 192];
        atomicAdd(&bnstats[tid], s);
        atomicAdd(&bnstats[64 + tid], q);
    }
}

// ---------------- finalize BN: scale/shift per channel ----------------
__global__ void k_bnfinish(const float* __restrict__ bnstats,
                           const float* __restrict__ gamma, const float* __restrict__ beta,
                           float* __restrict__ scale, float* __restrict__ shift, int N) {
    int c = threadIdx.x;
    float inv_n = 1.0f / (float)N;
    float mean = bnstats[c] * inv_n;
    float var = bnstats[64 + c] * inv_n - mean * mean;
    float sc = gamma[c] * rsqrtf(fmaxf(var, 0.f) + BN_EPS);
    scale[c] = sc;
    shift[c] = beta[c] - mean * sc;
}

// ---------------- apply BN + ReLU in place (float4) ----------------
__global__ void k_bnapply(float* __restrict__ h, const float* __restrict__ scale,
                          const float* __restrict__ shift, int N) {
    int t = blockIdx.x * blockDim.x + threadIdx.x;
    if (t >= N * 16) return;
    int idx = t * 4;
    int c = idx & 63;
    float4 v = *(const float4*)&h[idx];
    float4 sc = *(const float4*)&scale[c];
    float4 sf = *(const float4*)&shift[c];
    float4 r;
    r.x = fmaxf(v.x * sc.x + sf.x, 0.f);
    r.y = fmaxf(v.y * sc.y + sf.y, 0.f);
    r.z = fmaxf(v.z * sc.z + sf.z, 0.f);
    r.w = fmaxf(v.w * sc.w + sf.w, 0.f);
    *(float4*)&h[idx] = r;
}

// ---------------- pool per graph (sorted batch, binary search) + MLP head -------
__global__ void k_pool(const float* __restrict__ h, const int* __restrict__ batch,
                       const float* __restrict__ Wl1, const float* __restrict__ bl1,
                       const float* __restrict__ Wl2, const float* __restrict__ bl2,
                       float* __restrict__ out, int N) {
    int g = blockIdx.x;
    int c = threadIdx.x;  // 64 threads
    int lo = 0, hi = N;
    while (lo < hi) { int mid = (lo + hi) >> 1; if (batch[mid] < g) lo = mid + 1; else hi = mid; }
    int start = lo;
    hi = N;
    while (lo < hi) { int mid = (lo + hi) >> 1; if (batch[mid] < g + 1) lo = mid + 1; else hi = mid; }
    int end = lo;
    float acc = 0.f;
    for (int n = start; n < end; ++n) acc += h[(size_t)n * 64 + c];
    int cnt = end - start;
    float denom = (float)(cnt > 0 ? cnt : 1);
    __shared__ float gS[64], yS[64];
    gS[c] = acc / denom;
    __syncthreads();
    float y = bl1[c];
    for (int k = 0; k < 64; ++k) y += gS[k] * Wl1[k * 64 + c];
    yS[c] = fmaxf(y, 0.f);
    __syncthreads();
    if (c < 3) {
        float o = bl2[c];
        for (int k = 0; k < 64; ++k) o += yS[k] * Wl2[k * 3 + c];
        out[g * 3 + c] = o;
    }
}

extern "C" void kernel_launch(void* const* d_in, const int* in_sizes, int n_in,
                              void* d_out, int out_size, void* d_ws, size_t ws_size,
                              hipStream_t stream) {
    const float* x     = (const float*)d_in[0];
    const int*   eid   = (const int*)d_in[1];
    const float* attr  = (const float*)d_in[2];
    const int*   batch = (const int*)d_in[3];
    const float* Wemb  = (const float*)d_in[4];
    const float* bemb  = (const float*)d_in[5];
    const float* W1    = (const float*)d_in[6];
    const float* b1    = (const float*)d_in[7];
    const float* W2    = (const float*)d_in[8];
    const float* W3    = (const float*)d_in[9];
    const float* b3    = (const float*)d_in[10];
    const float* gamma = (const float*)d_in[11];
    const float* beta  = (const float*)d_in[12];
    const float* Wl1   = (const float*)d_in[13];
    const float* bl1   = (const float*)d_in[14];
    const float* Wl2   = (const float*)d_in[15];
    const float* bl2   = (const float*)d_in[16];

    int N = in_sizes[3];         // batch has N entries
    int E = in_sizes[2];         // EdgeAttr has E entries
    int L = in_sizes[7] / 64;    // b1 is [L,64]
    int G = out_size / 3;        // NUM_GRAPHS

    const int* src = eid;
    const int* dst = eid + E;

    float* ws      = (float*)d_ws;
    float* h       = ws;                       // N*64
    float* S       = h + (size_t)N * 64;       // N*64
    float* degw    = S + (size_t)N * 64;       // N
    float* bnstats = degw + N;                 // 128
    float* bnscale = bnstats + 128;            // 64
    float* bnshift = bnscale + 64;             // 64
    int*   deg     = (int*)(bnshift + 64);     // N
    int*   rowptr  = deg + N;                  // N+1
    int*   cursor  = rowptr + (N + 1);         // N
    int*   csrc    = cursor + N;               // E
    float* cattr   = (float*)(csrc + E);       // E

    // ---- CSR build (per call; inputs/ws are re-poisoned before every launch) ----
    hipMemsetAsync(deg, 0, (size_t)N * sizeof(int), stream);
    k_embed<<<(N * 64 + 255) / 256, 256, 0, stream>>>(x, Wemb, bemb, h, N);
    k_hist<<<(E + 255) / 256, 256, 0, stream>>>(dst, deg, E);
    k_scan<<<1, 1024, 0, stream>>>(deg, rowptr, cursor, N);
    k_fill<<<(E + 255) / 256, 256, 0, stream>>>(src, dst, attr, cursor, csrc, cattr, E);

    for (int l = 0; l < L; ++l) {
        hipMemsetAsync(bnstats, 0, 128 * sizeof(float), stream);
        k_gather<<<(N * 64 + 255) / 256, 256, 0, stream>>>(rowptr, csrc, cattr, h, S, degw, N);
        k_update<<<512, 256, 0, stream>>>(S, h, degw,
                                          W1 + (size_t)l * 4096, b1 + (size_t)l * 64,
                                          W2 + (size_t)l * 4096, W3 + (size_t)l * 4096,
                                          b3 + (size_t)l * 64, bnstats, N);
        k_bnfinish<<<1, 64, 0, stream>>>(bnstats, gamma + (size_t)l * 64, beta + (size_t)l * 64,
                                         bnscale, bnshift, N);
        k_bnapply<<<(N * 16 + 255) / 256, 256, 0, stream>>>(h, bnscale, bnshift, N);
    }

    k_pool<<<G, 64, 0, stream>>>(h, batch, Wl1, bl1, Wl2, bl2, (float*)d_out, N);
}

// Round 3
// 775.984 us; speedup vs baseline: 1.7105x; 1.3315x over previous
//
#include <hip/hip_runtime.h>

#define BN_EPS 1e-5f

// ---------------- embedding: h = x @ W_emb + b_emb  (x is [N,4]) ----------------
__global__ void k_embed(const float* __restrict__ x, const float* __restrict__ Wemb,
                        const float* __restrict__ bemb, float* __restrict__ h, int N) {
    int t = blockIdx.x * blockDim.x + threadIdx.x;
    int n = t >> 6, c = t & 63;
    if (n >= N) return;
    const float* xr = x + (size_t)n * 4;
    float acc = bemb[c];
    acc += xr[0] * Wemb[0 * 64 + c];
    acc += xr[1] * Wemb[1 * 64 + c];
    acc += xr[2] * Wemb[2 * 64 + c];
    acc += xr[3] * Wemb[3 * 64 + c];
    h[t] = acc;  // t == n*64+c
}

// ---------------- CSR build: histogram of dst ----------------
__global__ void k_hist(const int* __restrict__ dst, int* __restrict__ deg, int E) {
    int e = blockIdx.x * blockDim.x + threadIdx.x;
    if (e < E) atomicAdd(&deg[dst[e]], 1);
}

// ---------------- scan phase 1: per-block sums (1024 elems / 256-thread block) --
__global__ __launch_bounds__(256) void k_blocksum(const int* __restrict__ deg,
                                                  int* __restrict__ bsum, int N) {
    __shared__ int red[256];
    int tid = threadIdx.x;
    int base = blockIdx.x * 1024 + tid * 4;
    int s = 0;
    if (base + 3 < N) {
        int4 v = *(const int4*)&deg[base];
        s = v.x + v.y + v.z + v.w;
    } else {
        for (int i = 0; i < 4; ++i) if (base + i < N) s += deg[base + i];
    }
    red[tid] = s;
    __syncthreads();
    for (int d = 128; d > 0; d >>= 1) {
        if (tid < d) red[tid] += red[tid + d];
        __syncthreads();
    }
    if (tid == 0) bsum[blockIdx.x] = red[0];
}

// ---------------- scan phase 2: exclusive scan of block sums (nb <= 1024) -------
__global__ __launch_bounds__(1024) void k_scanpartials(int* __restrict__ bsum, int nb) {
    __shared__ int t[1024];
    int tid = threadIdx.x;
    int v = (tid < nb) ? bsum[tid] : 0;
    t[tid] = v;
    __syncthreads();
    for (int d = 1; d < 1024; d <<= 1) {
        int u = (tid >= d) ? t[tid - d] : 0;
        __syncthreads();
        t[tid] += u;
        __syncthreads();
    }
    if (tid < nb) bsum[tid] = t[tid] - v;  // exclusive
}

// ---------------- scan phase 3: per-block exclusive scan + offset, write rowptr -
__global__ __launch_bounds__(256) void k_applyscan(const int* __restrict__ deg,
                                                   const int* __restrict__ bsum,
                                                   int* __restrict__ rowptr,
                                                   int* __restrict__ cursor, int N, int E) {
    __shared__ int red[256];
    int tid = threadIdx.x;
    int base = blockIdx.x * 1024 + tid * 4;
    int v0 = 0, v1 = 0, v2 = 0, v3 = 0;
    if (base + 3 < N) {
        int4 v = *(const int4*)&deg[base];
        v0 = v.x; v1 = v.y; v2 = v.z; v3 = v.w;
    } else {
        if (base < N) v0 = deg[base];
        if (base + 1 < N) v1 = deg[base + 1];
        if (base + 2 < N) v2 = deg[base + 2];
        if (base + 3 < N) v3 = deg[base + 3];
    }
    int s = v0 + v1 + v2 + v3;
    red[tid] = s;
    __syncthreads();
    for (int d = 1; d < 256; d <<= 1) {  // Hillis-Steele inclusive
        int u = (tid >= d) ? red[tid - d] : 0;
        __syncthreads();
        red[tid] += u;
        __syncthreads();
    }
    int off = bsum[blockIdx.x] + red[tid] - s;  // exclusive prefix for this thread
    int r0 = off, r1 = off + v0, r2 = r1 + v1, r3 = r2 + v2;
    if (base < N)     { rowptr[base] = r0;     cursor[base] = r0; }
    if (base + 1 < N) { rowptr[base + 1] = r1; cursor[base + 1] = r1; }
    if (base + 2 < N) { rowptr[base + 2] = r2; cursor[base + 2] = r2; }
    if (base + 3 < N) { rowptr[base + 3] = r3; cursor[base + 3] = r3; }
    if (blockIdx.x == 0 && tid == 0) rowptr[N] = E;
}

// ---------------- CSR build: fill sorted-by-dst edge arrays ----------------
__global__ void k_fill(const int* __restrict__ src, const int* __restrict__ dst,
                       const float* __restrict__ attr, int* __restrict__ cursor,
                       int* __restrict__ csrc, float* __restrict__ cattr, int E) {
    int e = blockIdx.x * blockDim.x + threadIdx.x;
    if (e >= E) return;
    int d = dst[e];
    int pos = atomicAdd(&cursor[d], 1);
    csrc[pos] = src[e];
    cattr[pos] = attr[e];
}

// ---------------- pull gather: S[n] = sum_e w_e * h[src_e]; degw[n] = sum w_e ---
__global__ void k_gather(const int* __restrict__ rowptr, const int* __restrict__ csrc,
                         const float* __restrict__ cattr, const float* __restrict__ h,
                         float* __restrict__ S, float* __restrict__ degw, int N) {
    int t = blockIdx.x * blockDim.x + threadIdx.x;
    int n = t >> 6, c = t & 63;
    if (n >= N) return;
    int beg = rowptr[n], end = rowptr[n + 1];
    float a0 = 0.f, a1 = 0.f, a2 = 0.f, a3 = 0.f;
    float w0s = 0.f;
    int e = beg;
    for (; e + 3 < end; e += 4) {
        int s0 = csrc[e], s1 = csrc[e + 1], s2 = csrc[e + 2], s3 = csrc[e + 3];
        float w0 = cattr[e], w1 = cattr[e + 1], w2 = cattr[e + 2], w3 = cattr[e + 3];
        a0 += w0 * h[(size_t)s0 * 64 + c];
        a1 += w1 * h[(size_t)s1 * 64 + c];
        a2 += w2 * h[(size_t)s2 * 64 + c];
        a3 += w3 * h[(size_t)s3 * 64 + c];
        w0s += w0 + w1 + w2 + w3;
    }
    for (; e < end; ++e) {
        int s0 = csrc[e];
        float w0 = cattr[e];
        a0 += w0 * h[(size_t)s0 * 64 + c];
        w0s += w0;
    }
    S[(size_t)n * 64 + c] = (a0 + a1) + (a2 + a3);
    if (c == 0) degw[n] = w0s;
}

// ------- h = S@W1 + h@W3 - degw*(h@W2) + degw*b1 + b3 (in place); BN partials ---
__global__ __launch_bounds__(256) void k_update(
    const float* __restrict__ S, float* __restrict__ h,
    const float* __restrict__ degw,
    const float* __restrict__ W1, const float* __restrict__ b1,
    const float* __restrict__ W2, const float* __restrict__ W3,
    const float* __restrict__ b3,
    float* __restrict__ bnstats, int N) {
    __shared__ float W1s[64 * 64], W2s[64 * 64], W3s[64 * 64];
    __shared__ float sS[16 * 64], sh[16 * 64];
    __shared__ float dwS[16];
    int tid = threadIdx.x;
    for (int i = tid * 4; i < 4096; i += 1024) {
        *(float4*)&W1s[i] = *(const float4*)&W1[i];
        *(float4*)&W2s[i] = *(const float4*)&W2[i];
        *(float4*)&W3s[i] = *(const float4*)&W3[i];
    }
    int c = tid & 63, w = tid >> 6;
    float b1c = b1[c], b3c = b3[c];
    float bsum = 0.f, bsq = 0.f;
    int numTiles = (N + 15) / 16;
    for (int tile = blockIdx.x; tile < numTiles; tile += gridDim.x) {
        int n0 = tile * 16;
        __syncthreads();
        {
            int idx = tid * 4;
            int nrow = idx >> 6;
            if (n0 + nrow < N) {
                int base = n0 * 64;
                *(float4*)&sS[idx] = *(const float4*)&S[base + idx];
                *(float4*)&sh[idx] = *(const float4*)&h[base + idx];
            } else {
                sS[idx] = sS[idx + 1] = sS[idx + 2] = sS[idx + 3] = 0.f;
                sh[idx] = sh[idx + 1] = sh[idx + 2] = sh[idx + 3] = 0.f;
            }
            if (tid < 16) dwS[tid] = (n0 + tid < N) ? degw[n0 + tid] : 0.f;
        }
        __syncthreads();
        float aA[4] = {0, 0, 0, 0}, aB[4] = {0, 0, 0, 0}, aC[4] = {0, 0, 0, 0};
        for (int k = 0; k < 64; ++k) {
            float w1 = W1s[k * 64 + c], w2 = W2s[k * 64 + c], w3 = W3s[k * 64 + c];
#pragma unroll
            for (int m = 0; m < 4; ++m) {
                int nl = w + 4 * m;
                float sv = sS[nl * 64 + k], hv = sh[nl * 64 + k];
                aA[m] += sv * w1;
                aB[m] += hv * w2;
                aC[m] += hv * w3;
            }
        }
#pragma unroll
        for (int m = 0; m < 4; ++m) {
            int nl = w + 4 * m;
            int n = n0 + nl;
            if (n < N) {
                float dw = dwS[nl];
                float val = aA[m] + aC[m] - dw * aB[m] + dw * b1c + b3c;
                h[(size_t)n * 64 + c] = val;
                bsum += val;
                bsq += val * val;
            }
        }
    }
    __syncthreads();
    sS[tid] = bsum;
    sS[256 + tid] = bsq;
    __syncthreads();
    if (tid < 64) {
        float s = sS[tid] + sS[tid + 64] + sS[tid + 128] + sS[tid + 192];
        float q = sS[256 + tid] + sS[256 + tid + 64] + sS[256 + tid + 128] + sS[256 + tid + 192];
        atomicAdd(&bnstats[tid], s);
        atomicAdd(&bnstats[64 + tid], q);
    }
}

// ---------------- finalize BN: scale/shift per channel ----------------
__global__ void k_bnfinish(const float* __restrict__ bnstats,
                           const float* __restrict__ gamma, const float* __restrict__ beta,
                           float* __restrict__ scale, float* __restrict__ shift, int N) {
    int c = threadIdx.x;
    float inv_n = 1.0f / (float)N;
    float mean = bnstats[c] * inv_n;
    float var = bnstats[64 + c] * inv_n - mean * mean;
    float sc = gamma[c] * rsqrtf(fmaxf(var, 0.f) + BN_EPS);
    scale[c] = sc;
    shift[c] = beta[c] - mean * sc;
}

// ---------------- apply BN + ReLU in place (float4) ----------------
__global__ void k_bnapply(float* __restrict__ h, const float* __restrict__ scale,
                          const float* __restrict__ shift, int N) {
    int t = blockIdx.x * blockDim.x + threadIdx.x;
    if (t >= N * 16) return;
    int idx = t * 4;
    int c = idx & 63;
    float4 v = *(const float4*)&h[idx];
    float4 sc = *(const float4*)&scale[c];
    float4 sf = *(const float4*)&shift[c];
    float4 r;
    r.x = fmaxf(v.x * sc.x + sf.x, 0.f);
    r.y = fmaxf(v.y * sc.y + sf.y, 0.f);
    r.z = fmaxf(v.z * sc.z + sf.z, 0.f);
    r.w = fmaxf(v.w * sc.w + sf.w, 0.f);
    *(float4*)&h[idx] = r;
}

// ---------------- pool per graph (sorted batch, binary search) + MLP head -------
__global__ void k_pool(const float* __restrict__ h, const int* __restrict__ batch,
                       const float* __restrict__ Wl1, const float* __restrict__ bl1,
                       const float* __restrict__ Wl2, const float* __restrict__ bl2,
                       float* __restrict__ out, int N) {
    int g = blockIdx.x;
    int c = threadIdx.x;  // 64 threads
    int lo = 0, hi = N;
    while (lo < hi) { int mid = (lo + hi) >> 1; if (batch[mid] < g) lo = mid + 1; else hi = mid; }
    int start = lo;
    hi = N;
    while (lo < hi) { int mid = (lo + hi) >> 1; if (batch[mid] < g + 1) lo = mid + 1; else hi = mid; }
    int end = lo;
    float acc = 0.f;
    for (int n = start; n < end; ++n) acc += h[(size_t)n * 64 + c];
    int cnt = end - start;
    float denom = (float)(cnt > 0 ? cnt : 1);
    __shared__ float gS[64], yS[64];
    gS[c] = acc / denom;
    __syncthreads();
    float y = bl1[c];
    for (int k = 0; k < 64; ++k) y += gS[k] * Wl1[k * 64 + c];
    yS[c] = fmaxf(y, 0.f);
    __syncthreads();
    if (c < 3) {
        float o = bl2[c];
        for (int k = 0; k < 64; ++k) o += yS[k] * Wl2[k * 3 + c];
        out[g * 3 + c] = o;
    }
}

extern "C" void kernel_launch(void* const* d_in, const int* in_sizes, int n_in,
                              void* d_out, int out_size, void* d_ws, size_t ws_size,
                              hipStream_t stream) {
    const float* x     = (const float*)d_in[0];
    const int*   eid   = (const int*)d_in[1];
    const float* attr  = (const float*)d_in[2];
    const int*   batch = (const int*)d_in[3];
    const float* Wemb  = (const float*)d_in[4];
    const float* bemb  = (const float*)d_in[5];
    const float* W1    = (const float*)d_in[6];
    const float* b1    = (const float*)d_in[7];
    const float* W2    = (const float*)d_in[8];
    const float* W3    = (const float*)d_in[9];
    const float* b3    = (const float*)d_in[10];
    const float* gamma = (const float*)d_in[11];
    const float* beta  = (const float*)d_in[12];
    const float* Wl1   = (const float*)d_in[13];
    const float* bl1   = (const float*)d_in[14];
    const float* Wl2   = (const float*)d_in[15];
    const float* bl2   = (const float*)d_in[16];

    int N = in_sizes[3];
    int E = in_sizes[2];
    int L = in_sizes[7] / 64;
    int G = out_size / 3;

    const int* src = eid;
    const int* dst = eid + E;

    float* ws      = (float*)d_ws;
    float* h       = ws;                       // N*64
    float* S       = h + (size_t)N * 64;       // N*64
    float* degw    = S + (size_t)N * 64;       // N
    float* bnstats = degw + N;                 // 128
    float* bnscale = bnstats + 128;            // 64
    float* bnshift = bnscale + 64;             // 64
    int*   deg     = (int*)(bnshift + 64);     // N
    int*   rowptr  = deg + N;                  // N+1
    int*   cursor  = rowptr + (N + 1);         // N
    int*   bsum    = cursor + N;               // <= 1024
    int*   csrc    = bsum + 1024;              // E
    float* cattr   = (float*)(csrc + E);       // E

    int nScanBlocks = (N + 1023) / 1024;  // 1024 elems per block

    // ---- CSR build ----
    hipMemsetAsync(deg, 0, (size_t)N * sizeof(int), stream);
    k_embed<<<(N * 64 + 255) / 256, 256, 0, stream>>>(x, Wemb, bemb, h, N);
    k_hist<<<(E + 255) / 256, 256, 0, stream>>>(dst, deg, E);
    k_blocksum<<<nScanBlocks, 256, 0, stream>>>(deg, bsum, N);
    k_scanpartials<<<1, 1024, 0, stream>>>(bsum, nScanBlocks);
    k_applyscan<<<nScanBlocks, 256, 0, stream>>>(deg, bsum, rowptr, cursor, N, E);
    k_fill<<<(E + 255) / 256, 256, 0, stream>>>(src, dst, attr, cursor, csrc, cattr, E);

    for (int l = 0; l < L; ++l) {
        hipMemsetAsync(bnstats, 0, 128 * sizeof(float), stream);
        k_gather<<<(N * 64 + 255) / 256, 256, 0, stream>>>(rowptr, csrc, cattr, h, S, degw, N);
        k_update<<<512, 256, 0, stream>>>(S, h, degw,
                                          W1 + (size_t)l * 4096, b1 + (size_t)l * 64,
                                          W2 + (size_t)l * 4096, W3 + (size_t)l * 4096,
                                          b3 + (size_t)l * 64, bnstats, N);
        k_bnfinish<<<1, 64, 0, stream>>>(bnstats, gamma + (size_t)l * 64, beta + (size_t)l * 64,
                                         bnscale, bnshift, N);
        k_bnapply<<<(N * 16 + 255) / 256, 256, 0, stream>>>(h, bnscale, bnshift, N);
    }

    k_pool<<<G, 64, 0, stream>>>(h, batch, Wl1, bl1, Wl2, bl2, (float*)d_out, N);
}

// Round 4
// 694.884 us; speedup vs baseline: 1.9101x; 1.1167x over previous
//
#include <hip/hip_runtime.h>

#define BN_EPS 1e-5f

// ---------------- embedding: h = x @ W_emb + b_emb  (x is [N,4]) ----------------
__global__ void k_embed(const float* __restrict__ x, const float* __restrict__ Wemb,
                        const float* __restrict__ bemb, float* __restrict__ h, int N) {
    int t = blockIdx.x * blockDim.x + threadIdx.x;
    int n = t >> 6, c = t & 63;
    if (n >= N) return;
    const float* xr = x + (size_t)n * 4;
    float acc = bemb[c];
    acc += xr[0] * Wemb[0 * 64 + c];
    acc += xr[1] * Wemb[1 * 64 + c];
    acc += xr[2] * Wemb[2 * 64 + c];
    acc += xr[3] * Wemb[3 * 64 + c];
    h[t] = acc;  // t == n*64+c
}

// ---------------- CSR build: histogram of dst ----------------
__global__ void k_hist(const int* __restrict__ dst, int* __restrict__ deg, int E) {
    int e = blockIdx.x * blockDim.x + threadIdx.x;
    if (e < E) atomicAdd(&deg[dst[e]], 1);
}

// ---------------- scan phase 1: per-block sums (1024 elems / 256-thread block) --
__global__ __launch_bounds__(256) void k_blocksum(const int* __restrict__ deg,
                                                  int* __restrict__ bsum, int N) {
    __shared__ int red[256];
    int tid = threadIdx.x;
    int base = blockIdx.x * 1024 + tid * 4;
    int s = 0;
    if (base + 3 < N) {
        int4 v = *(const int4*)&deg[base];
        s = v.x + v.y + v.z + v.w;
    } else {
        for (int i = 0; i < 4; ++i) if (base + i < N) s += deg[base + i];
    }
    red[tid] = s;
    __syncthreads();
    for (int d = 128; d > 0; d >>= 1) {
        if (tid < d) red[tid] += red[tid + d];
        __syncthreads();
    }
    if (tid == 0) bsum[blockIdx.x] = red[0];
}

// ---------------- scan phase 2: exclusive scan of block sums (nb <= 1024) -------
__global__ __launch_bounds__(1024) void k_scanpartials(int* __restrict__ bsum, int nb) {
    __shared__ int t[1024];
    int tid = threadIdx.x;
    int v = (tid < nb) ? bsum[tid] : 0;
    t[tid] = v;
    __syncthreads();
    for (int d = 1; d < 1024; d <<= 1) {
        int u = (tid >= d) ? t[tid - d] : 0;
        __syncthreads();
        t[tid] += u;
        __syncthreads();
    }
    if (tid < nb) bsum[tid] = t[tid] - v;  // exclusive
}

// ---------------- scan phase 3: per-block exclusive scan + offset, write rowptr -
__global__ __launch_bounds__(256) void k_applyscan(const int* __restrict__ deg,
                                                   const int* __restrict__ bsum,
                                                   int* __restrict__ rowptr,
                                                   int* __restrict__ cursor, int N, int E) {
    __shared__ int red[256];
    int tid = threadIdx.x;
    int base = blockIdx.x * 1024 + tid * 4;
    int v0 = 0, v1 = 0, v2 = 0, v3 = 0;
    if (base + 3 < N) {
        int4 v = *(const int4*)&deg[base];
        v0 = v.x; v1 = v.y; v2 = v.z; v3 = v.w;
    } else {
        if (base < N) v0 = deg[base];
        if (base + 1 < N) v1 = deg[base + 1];
        if (base + 2 < N) v2 = deg[base + 2];
        if (base + 3 < N) v3 = deg[base + 3];
    }
    int s = v0 + v1 + v2 + v3;
    red[tid] = s;
    __syncthreads();
    for (int d = 1; d < 256; d <<= 1) {  // Hillis-Steele inclusive
        int u = (tid >= d) ? red[tid - d] : 0;
        __syncthreads();
        red[tid] += u;
        __syncthreads();
    }
    int off = bsum[blockIdx.x] + red[tid] - s;  // exclusive prefix for this thread
    int r0 = off, r1 = off + v0, r2 = r1 + v1, r3 = r2 + v2;
    if (base < N)     { rowptr[base] = r0;     cursor[base] = r0; }
    if (base + 1 < N) { rowptr[base + 1] = r1; cursor[base + 1] = r1; }
    if (base + 2 < N) { rowptr[base + 2] = r2; cursor[base + 2] = r2; }
    if (base + 3 < N) { rowptr[base + 3] = r3; cursor[base + 3] = r3; }
    if (blockIdx.x == 0 && tid == 0) rowptr[N] = E;
}

// ---------------- CSR build: fill sorted-by-dst edge arrays ----------------
__global__ void k_fill(const int* __restrict__ src, const int* __restrict__ dst,
                       const float* __restrict__ attr, int* __restrict__ cursor,
                       int* __restrict__ csrc, float* __restrict__ cattr, int E) {
    int e = blockIdx.x * blockDim.x + threadIdx.x;
    if (e >= E) return;
    int d = dst[e];
    int pos = atomicAdd(&cursor[d], 1);
    csrc[pos] = src[e];
    cattr[pos] = attr[e];
}

// ---------------- pull gather: S[n] = sum_e w_e * h[src_e]; degw[n] = sum w_e ---
__global__ void k_gather(const int* __restrict__ rowptr, const int* __restrict__ csrc,
                         const float* __restrict__ cattr, const float* __restrict__ h,
                         float* __restrict__ S, float* __restrict__ degw, int N) {
    int t = blockIdx.x * blockDim.x + threadIdx.x;
    int n = t >> 6, c = t & 63;
    if (n >= N) return;
    int beg = rowptr[n], end = rowptr[n + 1];
    float a0 = 0.f, a1 = 0.f, a2 = 0.f, a3 = 0.f;
    float w0s = 0.f;
    int e = beg;
    for (; e + 3 < end; e += 4) {
        int s0 = csrc[e], s1 = csrc[e + 1], s2 = csrc[e + 2], s3 = csrc[e + 3];
        float w0 = cattr[e], w1 = cattr[e + 1], w2 = cattr[e + 2], w3 = cattr[e + 3];
        a0 += w0 * h[(size_t)s0 * 64 + c];
        a1 += w1 * h[(size_t)s1 * 64 + c];
        a2 += w2 * h[(size_t)s2 * 64 + c];
        a3 += w3 * h[(size_t)s3 * 64 + c];
        w0s += w0 + w1 + w2 + w3;
    }
    for (; e < end; ++e) {
        int s0 = csrc[e];
        float w0 = cattr[e];
        a0 += w0 * h[(size_t)s0 * 64 + c];
        w0s += w0;
    }
    S[(size_t)n * 64 + c] = (a0 + a1) + (a2 + a3);
    if (c == 0) degw[n] = w0s;
}

// ------- h = S@W1 + h@W3 - degw*(h@W2) + degw*b1 + b3 (in place); BN partials ---
__global__ __launch_bounds__(256) void k_update(
    const float* __restrict__ S, float* __restrict__ h,
    const float* __restrict__ degw,
    const float* __restrict__ W1, const float* __restrict__ b1,
    const float* __restrict__ W2, const float* __restrict__ W3,
    const float* __restrict__ b3,
    float* __restrict__ bnstats, int N) {
    __shared__ float W1s[64 * 64], W2s[64 * 64], W3s[64 * 64];
    __shared__ float sS[16 * 64], sh[16 * 64];
    __shared__ float dwS[16];
    int tid = threadIdx.x;
    for (int i = tid * 4; i < 4096; i += 1024) {
        *(float4*)&W1s[i] = *(const float4*)&W1[i];
        *(float4*)&W2s[i] = *(const float4*)&W2[i];
        *(float4*)&W3s[i] = *(const float4*)&W3[i];
    }
    int c = tid & 63, w = tid >> 6;
    float b1c = b1[c], b3c = b3[c];
    float bsum = 0.f, bsq = 0.f;
    int numTiles = (N + 15) / 16;
    for (int tile = blockIdx.x; tile < numTiles; tile += gridDim.x) {
        int n0 = tile * 16;
        __syncthreads();
        {
            int idx = tid * 4;
            int nrow = idx >> 6;
            if (n0 + nrow < N) {
                int base = n0 * 64;
                *(float4*)&sS[idx] = *(const float4*)&S[base + idx];
                *(float4*)&sh[idx] = *(const float4*)&h[base + idx];
            } else {
                sS[idx] = sS[idx + 1] = sS[idx + 2] = sS[idx + 3] = 0.f;
                sh[idx] = sh[idx + 1] = sh[idx + 2] = sh[idx + 3] = 0.f;
            }
            if (tid < 16) dwS[tid] = (n0 + tid < N) ? degw[n0 + tid] : 0.f;
        }
        __syncthreads();
        float aA[4] = {0, 0, 0, 0}, aB[4] = {0, 0, 0, 0}, aC[4] = {0, 0, 0, 0};
        for (int k = 0; k < 64; ++k) {
            float w1 = W1s[k * 64 + c], w2 = W2s[k * 64 + c], w3 = W3s[k * 64 + c];
#pragma unroll
            for (int m = 0; m < 4; ++m) {
                int nl = w + 4 * m;
                float sv = sS[nl * 64 + k], hv = sh[nl * 64 + k];
                aA[m] += sv * w1;
                aB[m] += hv * w2;
                aC[m] += hv * w3;
            }
        }
#pragma unroll
        for (int m = 0; m < 4; ++m) {
            int nl = w + 4 * m;
            int n = n0 + nl;
            if (n < N) {
                float dw = dwS[nl];
                float val = aA[m] + aC[m] - dw * aB[m] + dw * b1c + b3c;
                h[(size_t)n * 64 + c] = val;
                bsum += val;
                bsq += val * val;
            }
        }
    }
    __syncthreads();
    sS[tid] = bsum;
    sS[256 + tid] = bsq;
    __syncthreads();
    if (tid < 64) {
        float s = sS[tid] + sS[tid + 64] + sS[tid + 128] + sS[tid + 192];
        float q = sS[256 + tid] + sS[256 + tid + 64] + sS[256 + tid + 128] + sS[256 + tid + 192];
        atomicAdd(&bnstats[tid], s);
        atomicAdd(&bnstats[64 + tid], q);
    }
}

// ---------------- finalize BN: scale/shift per channel ----------------
__global__ void k_bnfinish(const float* __restrict__ bnstats,
                           const float* __restrict__ gamma, const float* __restrict__ beta,
                           float* __restrict__ scale, float* __restrict__ shift, int N) {
    int c = threadIdx.x;
    float inv_n = 1.0f / (float)N;
    float mean = bnstats[c] * inv_n;
    float var = bnstats[64 + c] * inv_n - mean * mean;
    float sc = gamma[c] * rsqrtf(fmaxf(var, 0.f) + BN_EPS);
    scale[c] = sc;
    shift[c] = beta[c] - mean * sc;
}

// ---------------- apply BN + ReLU in place (float4) ----------------
__global__ void k_bnapply(float* __restrict__ h, const float* __restrict__ scale,
                          const float* __restrict__ shift, int N) {
    int t = blockIdx.x * blockDim.x + threadIdx.x;
    if (t >= N * 16) return;
    int idx = t * 4;
    int c = idx & 63;
    float4 v = *(const float4*)&h[idx];
    float4 sc = *(const float4*)&scale[c];
    float4 sf = *(const float4*)&shift[c];
    float4 r;
    r.x = fmaxf(v.x * sc.x + sf.x, 0.f);
    r.y = fmaxf(v.y * sc.y + sf.y, 0.f);
    r.z = fmaxf(v.z * sc.z + sf.z, 0.f);
    r.w = fmaxf(v.w * sc.w + sf.w, 0.f);
    *(float4*)&h[idx] = r;
}

// ------- pool phase 1: per-graph sums via sorted-run accumulation + atomics -----
// Block covers POOL_TILE contiguous nodes; 4 waves interleave over nodes (stride 4).
// Each thread keeps a running (graph, acc) and flushes on graph change (batch sorted).
#define POOL_TILE 128
__global__ __launch_bounds__(256) void k_poolsum(const float* __restrict__ h,
                                                 const int* __restrict__ batch,
                                                 float* __restrict__ gsums, int N) {
    int tid = threadIdx.x;
    int c = tid & 63, q = tid >> 6;  // channel, node-stride group (0..3)
    int n0 = blockIdx.x * POOL_TILE;
    int nEnd = n0 + POOL_TILE; if (nEnd > N) nEnd = N;
    int g = -1;
    float acc = 0.f;
    for (int n = n0 + q; n < nEnd; n += 4) {
        int b = batch[n];
        if (b != g) {
            if (g >= 0) atomicAdd(&gsums[(size_t)g * 64 + c], acc);
            g = b; acc = 0.f;
        }
        acc += h[(size_t)n * 64 + c];
    }
    if (g >= 0) atomicAdd(&gsums[(size_t)g * 64 + c], acc);
}

// ------- pool phase 2: divide by count + MLP head (one 64-thread block / graph) -
__global__ void k_head(const float* __restrict__ gsums, const int* __restrict__ batch,
                       const float* __restrict__ Wl1, const float* __restrict__ bl1,
                       const float* __restrict__ Wl2, const float* __restrict__ bl2,
                       float* __restrict__ out, int N) {
    int g = blockIdx.x;
    int c = threadIdx.x;  // 64 threads
    int lo = 0, hi = N;
    while (lo < hi) { int mid = (lo + hi) >> 1; if (batch[mid] < g) lo = mid + 1; else hi = mid; }
    int start = lo;
    hi = N;
    while (lo < hi) { int mid = (lo + hi) >> 1; if (batch[mid] < g + 1) lo = mid + 1; else hi = mid; }
    int cnt = lo - start;
    float denom = (float)(cnt > 0 ? cnt : 1);
    __shared__ float gS[64], yS[64];
    gS[c] = gsums[(size_t)g * 64 + c] / denom;
    __syncthreads();
    float y = bl1[c];
    for (int k = 0; k < 64; ++k) y += gS[k] * Wl1[k * 64 + c];
    yS[c] = fmaxf(y, 0.f);
    __syncthreads();
    if (c < 3) {
        float o = bl2[c];
        for (int k = 0; k < 64; ++k) o += yS[k] * Wl2[k * 3 + c];
        out[g * 3 + c] = o;
    }
}

extern "C" void kernel_launch(void* const* d_in, const int* in_sizes, int n_in,
                              void* d_out, int out_size, void* d_ws, size_t ws_size,
                              hipStream_t stream) {
    const float* x     = (const float*)d_in[0];
    const int*   eid   = (const int*)d_in[1];
    const float* attr  = (const float*)d_in[2];
    const int*   batch = (const int*)d_in[3];
    const float* Wemb  = (const float*)d_in[4];
    const float* bemb  = (const float*)d_in[5];
    const float* W1    = (const float*)d_in[6];
    const float* b1    = (const float*)d_in[7];
    const float* W2    = (const float*)d_in[8];
    const float* W3    = (const float*)d_in[9];
    const float* b3    = (const float*)d_in[10];
    const float* gamma = (const float*)d_in[11];
    const float* beta  = (const float*)d_in[12];
    const float* Wl1   = (const float*)d_in[13];
    const float* bl1   = (const float*)d_in[14];
    const float* Wl2   = (const float*)d_in[15];
    const float* bl2   = (const float*)d_in[16];

    int N = in_sizes[3];
    int E = in_sizes[2];
    int L = in_sizes[7] / 64;
    int G = out_size / 3;

    const int* src = eid;
    const int* dst = eid + E;

    float* ws      = (float*)d_ws;
    float* h       = ws;                       // N*64
    float* S       = h + (size_t)N * 64;       // N*64
    float* degw    = S + (size_t)N * 64;       // N
    float* bnstats = degw + N;                 // 128
    float* bnscale = bnstats + 128;            // 64
    float* bnshift = bnscale + 64;             // 64
    float* gsums   = bnshift + 64;             // G*64
    int*   deg     = (int*)(gsums + (size_t)G * 64);  // N
    int*   rowptr  = deg + N;                  // N+1
    int*   cursor  = rowptr + (N + 1);         // N
    int*   bsum    = cursor + N;               // <= 1024
    int*   csrc    = bsum + 1024;              // E
    float* cattr   = (float*)(csrc + E);       // E

    int nScanBlocks = (N + 1023) / 1024;  // 1024 elems per block

    // ---- CSR build ----
    hipMemsetAsync(deg, 0, (size_t)N * sizeof(int), stream);
    k_embed<<<(N * 64 + 255) / 256, 256, 0, stream>>>(x, Wemb, bemb, h, N);
    k_hist<<<(E + 255) / 256, 256, 0, stream>>>(dst, deg, E);
    k_blocksum<<<nScanBlocks, 256, 0, stream>>>(deg, bsum, N);
    k_scanpartials<<<1, 1024, 0, stream>>>(bsum, nScanBlocks);
    k_applyscan<<<nScanBlocks, 256, 0, stream>>>(deg, bsum, rowptr, cursor, N, E);
    k_fill<<<(E + 255) / 256, 256, 0, stream>>>(src, dst, attr, cursor, csrc, cattr, E);

    for (int l = 0; l < L; ++l) {
        hipMemsetAsync(bnstats, 0, 128 * sizeof(float), stream);
        k_gather<<<(N * 64 + 255) / 256, 256, 0, stream>>>(rowptr, csrc, cattr, h, S, degw, N);
        k_update<<<512, 256, 0, stream>>>(S, h, degw,
                                          W1 + (size_t)l * 4096, b1 + (size_t)l * 64,
                                          W2 + (size_t)l * 4096, W3 + (size_t)l * 4096,
                                          b3 + (size_t)l * 64, bnstats, N);
        k_bnfinish<<<1, 64, 0, stream>>>(bnstats, gamma + (size_t)l * 64, beta + (size_t)l * 64,
                                         bnscale, bnshift, N);
        k_bnapply<<<(N * 16 + 255) / 256, 256, 0, stream>>>(h, bnscale, bnshift, N);
    }

    // ---- pool + head ----
    hipMemsetAsync(gsums, 0, (size_t)G * 64 * sizeof(float), stream);
    k_poolsum<<<(N + POOL_TILE - 1) / POOL_TILE, 256, 0, stream>>>(h, batch, gsums, N);
    k_head<<<G, 64, 0, stream>>>(gsums, batch, Wl1, bl1, Wl2, bl2, (float*)d_out, N);
}

// Round 5
// 691.318 us; speedup vs baseline: 1.9200x; 1.0052x over previous
//
#include <hip/hip_runtime.h>

#define BN_EPS 1e-5f

// ---------------- embedding: h = x @ W_emb + b_emb  (x is [N,4]) ----------------
__global__ void k_embed(const float* __restrict__ x, const float* __restrict__ Wemb,
                        const float* __restrict__ bemb, float* __restrict__ h, int N) {
    int t = blockIdx.x * blockDim.x + threadIdx.x;
    int n = t >> 6, c = t & 63;
    if (n >= N) return;
    const float* xr = x + (size_t)n * 4;
    float acc = bemb[c];
    acc += xr[0] * Wemb[0 * 64 + c];
    acc += xr[1] * Wemb[1 * 64 + c];
    acc += xr[2] * Wemb[2 * 64 + c];
    acc += xr[3] * Wemb[3 * 64 + c];
    h[t] = acc;  // t == n*64+c
}

// ---------------- CSR build: histogram of dst ----------------
__global__ void k_hist(const int* __restrict__ dst, int* __restrict__ deg, int E) {
    int e = blockIdx.x * blockDim.x + threadIdx.x;
    if (e < E) atomicAdd(&deg[dst[e]], 1);
}

// ---------------- scan phase 1: per-block sums (1024 elems / 256-thread block) --
__global__ __launch_bounds__(256) void k_blocksum(const int* __restrict__ deg,
                                                  int* __restrict__ bsum, int N) {
    __shared__ int red[256];
    int tid = threadIdx.x;
    int base = blockIdx.x * 1024 + tid * 4;
    int s = 0;
    if (base + 3 < N) {
        int4 v = *(const int4*)&deg[base];
        s = v.x + v.y + v.z + v.w;
    } else {
        for (int i = 0; i < 4; ++i) if (base + i < N) s += deg[base + i];
    }
    red[tid] = s;
    __syncthreads();
    for (int d = 128; d > 0; d >>= 1) {
        if (tid < d) red[tid] += red[tid + d];
        __syncthreads();
    }
    if (tid == 0) bsum[blockIdx.x] = red[0];
}

// ---------------- scan phase 2: exclusive scan of block sums (nb <= 1024) -------
__global__ __launch_bounds__(1024) void k_scanpartials(int* __restrict__ bsum, int nb) {
    __shared__ int t[1024];
    int tid = threadIdx.x;
    int v = (tid < nb) ? bsum[tid] : 0;
    t[tid] = v;
    __syncthreads();
    for (int d = 1; d < 1024; d <<= 1) {
        int u = (tid >= d) ? t[tid - d] : 0;
        __syncthreads();
        t[tid] += u;
        __syncthreads();
    }
    if (tid < nb) bsum[tid] = t[tid] - v;  // exclusive
}

// ---------------- scan phase 3: per-block exclusive scan + offset, write rowptr -
__global__ __launch_bounds__(256) void k_applyscan(const int* __restrict__ deg,
                                                   const int* __restrict__ bsum,
                                                   int* __restrict__ rowptr,
                                                   int* __restrict__ cursor, int N, int E) {
    __shared__ int red[256];
    int tid = threadIdx.x;
    int base = blockIdx.x * 1024 + tid * 4;
    int v0 = 0, v1 = 0, v2 = 0, v3 = 0;
    if (base + 3 < N) {
        int4 v = *(const int4*)&deg[base];
        v0 = v.x; v1 = v.y; v2 = v.z; v3 = v.w;
    } else {
        if (base < N) v0 = deg[base];
        if (base + 1 < N) v1 = deg[base + 1];
        if (base + 2 < N) v2 = deg[base + 2];
        if (base + 3 < N) v3 = deg[base + 3];
    }
    int s = v0 + v1 + v2 + v3;
    red[tid] = s;
    __syncthreads();
    for (int d = 1; d < 256; d <<= 1) {  // Hillis-Steele inclusive
        int u = (tid >= d) ? red[tid - d] : 0;
        __syncthreads();
        red[tid] += u;
        __syncthreads();
    }
    int off = bsum[blockIdx.x] + red[tid] - s;  // exclusive prefix for this thread
    int r0 = off, r1 = off + v0, r2 = r1 + v1, r3 = r2 + v2;
    if (base < N)     { rowptr[base] = r0;     cursor[base] = r0; }
    if (base + 1 < N) { rowptr[base + 1] = r1; cursor[base + 1] = r1; }
    if (base + 2 < N) { rowptr[base + 2] = r2; cursor[base + 2] = r2; }
    if (base + 3 < N) { rowptr[base + 3] = r3; cursor[base + 3] = r3; }
    if (blockIdx.x == 0 && tid == 0) rowptr[N] = E;
}

// ---------------- CSR build: fill packed (src, attr) sorted by dst --------------
// One 8B store per edge (vs two 4B stores to distant arrays): halves random
// line-churn writeback traffic.
__global__ void k_fill(const int* __restrict__ src, const int* __restrict__ dst,
                       const float* __restrict__ attr, int* __restrict__ cursor,
                       unsigned long long* __restrict__ edata, int E) {
    int e = blockIdx.x * blockDim.x + threadIdx.x;
    if (e >= E) return;
    int d = dst[e];
    int pos = atomicAdd(&cursor[d], 1);
    unsigned long long p = ((unsigned long long)__float_as_uint(attr[e]) << 32) |
                           (unsigned int)src[e];
    edata[pos] = p;
}

// ---------------- pull gather: S[n] = sum_e w_e * h[src_e]; degw[n] = sum w_e ---
__global__ void k_gather(const int* __restrict__ rowptr,
                         const unsigned long long* __restrict__ edata,
                         const float* __restrict__ h,
                         float* __restrict__ S, float* __restrict__ degw, int N) {
    int t = blockIdx.x * blockDim.x + threadIdx.x;
    int n = t >> 6, c = t & 63;
    if (n >= N) return;
    int beg = rowptr[n], end = rowptr[n + 1];
    float a0 = 0.f, a1 = 0.f, a2 = 0.f, a3 = 0.f;
    float w0s = 0.f;
    int e = beg;
    for (; e + 3 < end; e += 4) {
        unsigned long long p0 = edata[e],     p1 = edata[e + 1];
        unsigned long long p2 = edata[e + 2], p3 = edata[e + 3];
        int s0 = (int)(unsigned int)p0, s1 = (int)(unsigned int)p1;
        int s2 = (int)(unsigned int)p2, s3 = (int)(unsigned int)p3;
        float w0 = __uint_as_float((unsigned int)(p0 >> 32));
        float w1 = __uint_as_float((unsigned int)(p1 >> 32));
        float w2 = __uint_as_float((unsigned int)(p2 >> 32));
        float w3 = __uint_as_float((unsigned int)(p3 >> 32));
        a0 += w0 * h[(size_t)s0 * 64 + c];
        a1 += w1 * h[(size_t)s1 * 64 + c];
        a2 += w2 * h[(size_t)s2 * 64 + c];
        a3 += w3 * h[(size_t)s3 * 64 + c];
        w0s += (w0 + w1) + (w2 + w3);
    }
    for (; e < end; ++e) {
        unsigned long long p0 = edata[e];
        int s0 = (int)(unsigned int)p0;
        float w0 = __uint_as_float((unsigned int)(p0 >> 32));
        a0 += w0 * h[(size_t)s0 * 64 + c];
        w0s += w0;
    }
    S[(size_t)n * 64 + c] = (a0 + a1) + (a2 + a3);
    if (c == 0) degw[n] = w0s;
}

// ------- h = S@W1 + h@W3 - degw*(h@W2) + degw*b1 + b3 (in place); BN partials ---
__global__ __launch_bounds__(256) void k_update(
    const float* __restrict__ S, float* __restrict__ h,
    const float* __restrict__ degw,
    const float* __restrict__ W1, const float* __restrict__ b1,
    const float* __restrict__ W2, const float* __restrict__ W3,
    const float* __restrict__ b3,
    float* __restrict__ bnstats, int N) {
    __shared__ float W1s[64 * 64], W2s[64 * 64], W3s[64 * 64];
    __shared__ float sS[16 * 64], sh[16 * 64];
    __shared__ float dwS[16];
    int tid = threadIdx.x;
    for (int i = tid * 4; i < 4096; i += 1024) {
        *(float4*)&W1s[i] = *(const float4*)&W1[i];
        *(float4*)&W2s[i] = *(const float4*)&W2[i];
        *(float4*)&W3s[i] = *(const float4*)&W3[i];
    }
    int c = tid & 63, w = tid >> 6;
    float b1c = b1[c], b3c = b3[c];
    float bsum = 0.f, bsq = 0.f;
    int numTiles = (N + 15) / 16;
    for (int tile = blockIdx.x; tile < numTiles; tile += gridDim.x) {
        int n0 = tile * 16;
        __syncthreads();
        {
            int idx = tid * 4;
            int nrow = idx >> 6;
            if (n0 + nrow < N) {
                int base = n0 * 64;
                *(float4*)&sS[idx] = *(const float4*)&S[base + idx];
                *(float4*)&sh[idx] = *(const float4*)&h[base + idx];
            } else {
                sS[idx] = sS[idx + 1] = sS[idx + 2] = sS[idx + 3] = 0.f;
                sh[idx] = sh[idx + 1] = sh[idx + 2] = sh[idx + 3] = 0.f;
            }
            if (tid < 16) dwS[tid] = (n0 + tid < N) ? degw[n0 + tid] : 0.f;
        }
        __syncthreads();
        float aA[4] = {0, 0, 0, 0}, aB[4] = {0, 0, 0, 0}, aC[4] = {0, 0, 0, 0};
        for (int k = 0; k < 64; ++k) {
            float w1 = W1s[k * 64 + c], w2 = W2s[k * 64 + c], w3 = W3s[k * 64 + c];
#pragma unroll
            for (int m = 0; m < 4; ++m) {
                int nl = w + 4 * m;
                float sv = sS[nl * 64 + k], hv = sh[nl * 64 + k];
                aA[m] += sv * w1;
                aB[m] += hv * w2;
                aC[m] += hv * w3;
            }
        }
#pragma unroll
        for (int m = 0; m < 4; ++m) {
            int nl = w + 4 * m;
            int n = n0 + nl;
            if (n < N) {
                float dw = dwS[nl];
                float val = aA[m] + aC[m] - dw * aB[m] + dw * b1c + b3c;
                h[(size_t)n * 64 + c] = val;
                bsum += val;
                bsq += val * val;
            }
        }
    }
    __syncthreads();
    sS[tid] = bsum;
    sS[256 + tid] = bsq;
    __syncthreads();
    if (tid < 64) {
        float s = sS[tid] + sS[tid + 64] + sS[tid + 128] + sS[tid + 192];
        float q = sS[256 + tid] + sS[256 + tid + 64] + sS[256 + tid + 128] + sS[256 + tid + 192];
        atomicAdd(&bnstats[tid], s);
        atomicAdd(&bnstats[64 + tid], q);
    }
}

// ---------------- finalize BN: scale/shift per channel ----------------
__global__ void k_bnfinish(const float* __restrict__ bnstats,
                           const float* __restrict__ gamma, const float* __restrict__ beta,
                           float* __restrict__ scale, float* __restrict__ shift, int N) {
    int c = threadIdx.x;
    float inv_n = 1.0f / (float)N;
    float mean = bnstats[c] * inv_n;
    float var = bnstats[64 + c] * inv_n - mean * mean;
    float sc = gamma[c] * rsqrtf(fmaxf(var, 0.f) + BN_EPS);
    scale[c] = sc;
    shift[c] = beta[c] - mean * sc;
}

// ---------------- apply BN + ReLU in place (float4) ----------------
__global__ void k_bnapply(float* __restrict__ h, const float* __restrict__ scale,
                          const float* __restrict__ shift, int N) {
    int t = blockIdx.x * blockDim.x + threadIdx.x;
    if (t >= N * 16) return;
    int idx = t * 4;
    int c = idx & 63;
    float4 v = *(const float4*)&h[idx];
    float4 sc = *(const float4*)&scale[c];
    float4 sf = *(const float4*)&shift[c];
    float4 r;
    r.x = fmaxf(v.x * sc.x + sf.x, 0.f);
    r.y = fmaxf(v.y * sc.y + sf.y, 0.f);
    r.z = fmaxf(v.z * sc.z + sf.z, 0.f);
    r.w = fmaxf(v.w * sc.w + sf.w, 0.f);
    *(float4*)&h[idx] = r;
}

// ------- pool phase 1: per-graph sums via sorted-run accumulation + atomics -----
#define POOL_TILE 128
__global__ __launch_bounds__(256) void k_poolsum(const float* __restrict__ h,
                                                 const int* __restrict__ batch,
                                                 float* __restrict__ gsums, int N) {
    int tid = threadIdx.x;
    int c = tid & 63, q = tid >> 6;
    int n0 = blockIdx.x * POOL_TILE;
    int nEnd = n0 + POOL_TILE; if (nEnd > N) nEnd = N;
    int g = -1;
    float acc = 0.f;
    for (int n = n0 + q; n < nEnd; n += 4) {
        int b = batch[n];
        if (b != g) {
            if (g >= 0) atomicAdd(&gsums[(size_t)g * 64 + c], acc);
            g = b; acc = 0.f;
        }
        acc += h[(size_t)n * 64 + c];
    }
    if (g >= 0) atomicAdd(&gsums[(size_t)g * 64 + c], acc);
}

// ------- pool phase 2: divide by count + MLP head (one 64-thread block / graph) -
__global__ void k_head(const float* __restrict__ gsums, const int* __restrict__ batch,
                       const float* __restrict__ Wl1, const float* __restrict__ bl1,
                       const float* __restrict__ Wl2, const float* __restrict__ bl2,
                       float* __restrict__ out, int N) {
    int g = blockIdx.x;
    int c = threadIdx.x;  // 64 threads
    int lo = 0, hi = N;
    while (lo < hi) { int mid = (lo + hi) >> 1; if (batch[mid] < g) lo = mid + 1; else hi = mid; }
    int start = lo;
    hi = N;
    while (lo < hi) { int mid = (lo + hi) >> 1; if (batch[mid] < g + 1) lo = mid + 1; else hi = mid; }
    int cnt = lo - start;
    float denom = (float)(cnt > 0 ? cnt : 1);
    __shared__ float gS[64], yS[64];
    gS[c] = gsums[(size_t)g * 64 + c] / denom;
    __syncthreads();
    float y = bl1[c];
    for (int k = 0; k < 64; ++k) y += gS[k] * Wl1[k * 64 + c];
    yS[c] = fmaxf(y, 0.f);
    __syncthreads();
    if (c < 3) {
        float o = bl2[c];
        for (int k = 0; k < 64; ++k) o += yS[k] * Wl2[k * 3 + c];
        out[g * 3 + c] = o;
    }
}

extern "C" void kernel_launch(void* const* d_in, const int* in_sizes, int n_in,
                              void* d_out, int out_size, void* d_ws, size_t ws_size,
                              hipStream_t stream) {
    const float* x     = (const float*)d_in[0];
    const int*   eid   = (const int*)d_in[1];
    const float* attr  = (const float*)d_in[2];
    const int*   batch = (const int*)d_in[3];
    const float* Wemb  = (const float*)d_in[4];
    const float* bemb  = (const float*)d_in[5];
    const float* W1    = (const float*)d_in[6];
    const float* b1    = (const float*)d_in[7];
    const float* W2    = (const float*)d_in[8];
    const float* W3    = (const float*)d_in[9];
    const float* b3    = (const float*)d_in[10];
    const float* gamma = (const float*)d_in[11];
    const float* beta  = (const float*)d_in[12];
    const float* Wl1   = (const float*)d_in[13];
    const float* bl1   = (const float*)d_in[14];
    const float* Wl2   = (const float*)d_in[15];
    const float* bl2   = (const float*)d_in[16];

    int N = in_sizes[3];
    int E = in_sizes[2];
    int L = in_sizes[7] / 64;
    int G = out_size / 3;

    const int* src = eid;
    const int* dst = eid + E;

    float* ws      = (float*)d_ws;
    float* h       = ws;                       // N*64
    float* S       = h + (size_t)N * 64;       // N*64
    float* degw    = S + (size_t)N * 64;       // N
    float* bnstats = degw + N;                 // 128
    float* bnscale = bnstats + 128;            // 64
    float* bnshift = bnscale + 64;             // 64
    float* gsums   = bnshift + 64;             // G*64
    int*   deg     = (int*)(gsums + (size_t)G * 64);  // N
    int*   rowptr  = deg + N;                  // N+2 (padded for 8B alignment below)
    int*   cursor  = rowptr + (N + 2);         // N
    int*   bsum    = cursor + N;               // <= 1024
    unsigned long long* edata = (unsigned long long*)(bsum + 1024);  // E (8B aligned)

    int nScanBlocks = (N + 1023) / 1024;

    // ---- CSR build ----
    hipMemsetAsync(deg, 0, (size_t)N * sizeof(int), stream);
    k_embed<<<(N * 64 + 255) / 256, 256, 0, stream>>>(x, Wemb, bemb, h, N);
    k_hist<<<(E + 255) / 256, 256, 0, stream>>>(dst, deg, E);
    k_blocksum<<<nScanBlocks, 256, 0, stream>>>(deg, bsum, N);
    k_scanpartials<<<1, 1024, 0, stream>>>(bsum, nScanBlocks);
    k_applyscan<<<nScanBlocks, 256, 0, stream>>>(deg, bsum, rowptr, cursor, N, E);
    k_fill<<<(E + 255) / 256, 256, 0, stream>>>(src, dst, attr, cursor, edata, E);

    for (int l = 0; l < L; ++l) {
        hipMemsetAsync(bnstats, 0, 128 * sizeof(float), stream);
        k_gather<<<(N * 64 + 255) / 256, 256, 0, stream>>>(rowptr, edata, h, S, degw, N);
        k_update<<<512, 256, 0, stream>>>(S, h, degw,
                                          W1 + (size_t)l * 4096, b1 + (size_t)l * 64,
                                          W2 + (size_t)l * 4096, W3 + (size_t)l * 4096,
                                          b3 + (size_t)l * 64, bnstats, N);
        k_bnfinish<<<1, 64, 0, stream>>>(bnstats, gamma + (size_t)l * 64, beta + (size_t)l * 64,
                                         bnscale, bnshift, N);
        k_bnapply<<<(N * 16 + 255) / 256, 256, 0, stream>>>(h, bnscale, bnshift, N);
    }

    // ---- pool + head ----
    hipMemsetAsync(gsums, 0, (size_t)G * 64 * sizeof(float), stream);
    k_poolsum<<<(N + POOL_TILE - 1) / POOL_TILE, 256, 0, stream>>>(h, batch, gsums, N);
    k_head<<<G, 64, 0, stream>>>(gsums, batch, Wl1, bl1, Wl2, bl2, (float*)d_out, N);
}